// Round 12
// baseline (340.243 us; speedup 1.0000x reference)
//
#include <hip/hip_runtime.h>

#define NN 65536
#define NE 1048576
#define HID 80
#define TCAP 8192  // tmp slots per bucket (max raw bucket ~4.4K)
#define ECAP 8192  // erec slots per bucket (max padded bucket ~6.2K)
#define LCAP 4864  // p2m LDS record cache (mean 4096 + 12 sigma)

typedef unsigned int u32;
typedef unsigned short u16;
typedef unsigned long long u64;

typedef float v4f __attribute__((ext_vector_type(4)));

__device__ __forceinline__ u16 f2bf(float f) {
  u32 u = __float_as_uint(f);
  u = (u + 0x7fffu + ((u >> 16) & 1u)) >> 16;  // RNE
  return (u16)u;
}
__device__ __forceinline__ float bfhi(u32 packed) {
  return __uint_as_float(packed & 0xffff0000u);
}
__device__ __forceinline__ float bflo(u32 packed) {
  return __uint_as_float(packed << 16);
}
// nt loads ONLY for true read-once streams (r3/r6: nt on anything L2-reused
// regressed; L2 absorption is the asset on this workload).
__device__ __forceinline__ float4 ntload4f(const float4* p) {
  v4f v = __builtin_nontemporal_load((const v4f*)p);
  return make_float4(v.x, v.y, v.z, v.w);
}
__device__ __forceinline__ int ntloadi(const int* p) {
  return __builtin_nontemporal_load(p);
}

// ---- pass 1: LDS bucket sort (blocks 0..511, 2048 edges each) || k_in ----
// bucket = dst>>8. Per block: LDS hist+scan+scatter, ONE global atomic per
// (block,bucket) run reservation (131K global atomics vs 1M fine-grained),
// contiguous run writes into tmp[bucket]. 2048-edge blocks are the proven
// granularity (r10: 1024-edge blocks halved run length to 64B -> partial-
// line scatter, +13us prep. Keep runs >= 128B). r12: bkid[] LDS array
// written at scatter time replaces the 8-step binary search per record.
__global__ __launch_bounds__(256) void k_p1_in(const int* __restrict__ dst,
    const int* __restrict__ src, const float4* __restrict__ eattr,
    int* __restrict__ bcnt, uint4* __restrict__ tmp,
    const float* __restrict__ x, const float* __restrict__ W,
    const float* __restrict__ b, u16* __restrict__ hmain,
    u16* __restrict__ htail) {
  if (blockIdx.x < 512) {
    __shared__ int hist[256];
    __shared__ int lofs[257];
    __shared__ int gbase[256];
    __shared__ int sc[256];
    __shared__ uint4 buf[2048];  // 32KB
    __shared__ unsigned char bkid[2048];
    int t = threadIdx.x;
    hist[t] = 0;
    __syncthreads();
    uint4 rec[8];
    int bk[8], lr[8];
    int base = blockIdx.x * 2048 + t;
#pragma unroll
    for (int k = 0; k < 8; k++) {
      int idx = base + k * 256;
      int d = ntloadi(dst + idx);
      float4 ea = ntload4f(eattr + idx);
      int s = ntloadi(src + idx);
      u32 c01 = (u32)f2bf(ea.x) | ((u32)f2bf(ea.y) << 16);
      u32 c23 = (u32)f2bf(ea.z) | ((u32)f2bf(ea.w) << 16);
      rec[k] = make_uint4((u32)s, c01, c23, (u32)d);  // dst in .w
      bk[k] = d >> 8;
      lr[k] = atomicAdd(&hist[bk[k]], 1);  // LDS atomic
    }
    __syncthreads();
    int h = hist[t];
    gbase[t] = atomicAdd(&bcnt[t], h);  // reserve run in bucket t
    sc[t] = h;
    __syncthreads();
    for (int d = 1; d < 256; d <<= 1) {
      int v = (t >= d) ? sc[t - d] : 0;
      __syncthreads();
      sc[t] += v;
      __syncthreads();
    }
    lofs[t] = sc[t] - h;
    if (t == 255) lofs[256] = 2048;
    __syncthreads();
#pragma unroll
    for (int k = 0; k < 8; k++) {
      int slot = lofs[bk[k]] + lr[k];
      buf[slot] = rec[k];
      bkid[slot] = (unsigned char)bk[k];
    }
    __syncthreads();
    // write sorted runs contiguously; bucket id via direct bkid lookup
#pragma unroll
    for (int k = 0; k < 8; k++) {
      int j = t + k * 256;
      int lo = bkid[j];
      tmp[(size_t)lo * TCAP + gbase[lo] + (j - lofs[lo])] = buf[j];
    }
  } else {
    int idx = (blockIdx.x - 512) * 256 + threadIdx.x;
    if (idx >= NN * 10) return;
    int n = idx / 10, part = idx % 10;
    const float4* xr = (const float4*)(x + (size_t)n * 16);
    float4 x0 = xr[0], x1 = xr[1], x2 = xr[2], x3 = xr[3];
    const float xs[16] = {x0.x, x0.y, x0.z, x0.w, x1.x, x1.y, x1.z, x1.w,
                          x2.x, x2.y, x2.z, x2.w, x3.x, x3.y, x3.z, x3.w};
    float acc[8];
#pragma unroll
    for (int j = 0; j < 8; j++) acc[j] = b[part * 8 + j];
#pragma unroll
    for (int k = 0; k < 16; k++) {
#pragma unroll
      for (int j = 0; j < 8; j++) acc[j] += xs[k] * W[k * HID + part * 8 + j];
    }
    u32 p0 = (u32)f2bf(acc[0]) | ((u32)f2bf(acc[1]) << 16);
    u32 p1 = (u32)f2bf(acc[2]) | ((u32)f2bf(acc[3]) << 16);
    u32 p2 = (u32)f2bf(acc[4]) | ((u32)f2bf(acc[5]) << 16);
    u32 p3 = (u32)f2bf(acc[6]) | ((u32)f2bf(acc[7]) << 16);
    uint4 vv = make_uint4(p0, p1, p2, p3);
    if (part < 8)
      *(uint4*)(hmain + (size_t)n * 64 + part * 8) = vv;
    else
      *(uint4*)(htail + (size_t)n * 16 + (part - 8) * 8) = vv;
  }
}

// ---- pass 2 (r12: ONE-pass): one block (512 thr) per bucket, records
// cached in 76KB dynamic LDS during a single tmp sweep (kills the strided
// .w-only histogram sweep — full-line fetches for 4 used bytes). FIXED
// bucket base b*ECAP in erec (holes never read). Then: padded local scan
// -> counts/offs_fin -> place from LDS via cursors -> pad-zero ->
// degree-bucket classify (reversed: heaviest first).
__global__ __launch_bounds__(512) void k_p2m(const int* __restrict__ bcnt,
    const uint4* __restrict__ tmp, int* __restrict__ counts_tot,
    int* __restrict__ offs_fin, uint4* __restrict__ erec,
    int* __restrict__ brank, int* __restrict__ bidx, int* __restrict__ dcnt) {
  extern __shared__ uint4 rbuf[];  // LCAP records, 76KB (gfx950: 160KB/WG)
  __shared__ int hist[256];
  __shared__ int sc[256];
  __shared__ int noff[256];
  __shared__ int cur[256];
  int t = threadIdx.x;
  if (t < 256) {
    hist[t] = 0;
    cur[t] = 0;
  }
  __syncthreads();
  int b = blockIdx.x;
  int cnt = min(bcnt[b], LCAP);
  const uint4* tb = tmp + (size_t)b * TCAP;
  for (int j = t; j < cnt; j += 512) {
    uint4 r = tb[j];
    rbuf[j] = r;
    atomicAdd(&hist[r.w & 255], 1);  // LDS atomic
  }
  __syncthreads();
  int deg = 0;
  if (t < 256) {
    deg = hist[t];
    sc[t] = (deg + 7) & ~7;
  }
  __syncthreads();
  for (int d = 1; d < 256; d <<= 1) {
    int v = (t < 256 && t >= d) ? sc[t - d] : 0;
    __syncthreads();
    if (t < 256) sc[t] += v;
    __syncthreads();
  }
  if (t < 256) {
    int p = (deg + 7) & ~7;
    int off = b * ECAP + sc[t] - p;
    noff[t] = off;
    offs_fin[b * 256 + t] = off;
    counts_tot[b * 256 + t] = deg;
  }
  __syncthreads();
  for (int j = t; j < cnt; j += 512) {
    uint4 r = rbuf[j];
    int i = r.w & 255;
    int lr = atomicAdd(&cur[i], 1);  // LDS cursor
    erec[(size_t)noff[i] + lr] = make_uint4(r.x, r.y, r.z, 0u);
  }
  __syncthreads();
  if (t < 256) {
    int degp = (deg + 7) & ~7;
    uint4 z = make_uint4(0u, 0u, 0u, 0u);
    for (int e = deg; e < degp; e++) erec[(size_t)noff[t] + e] = z;
    // classify (waves 0..3 fully active -> per-wave ballots are complete)
    int n = b * 256 + t;
    int bb2 = 15 - min(degp >> 3, 15);
    int lane = t & 63;
    int base = 0;
#pragma unroll 1
    for (int bb = 0; bb < 16; bb++) {
      u64 m = __ballot(bb2 == bb);
      if (bb2 == bb) {
        int leader = __ffsll((long long)m) - 1;
        int lr = __popcll(m & ((lane == 63) ? ~0ull >> 1 : ((1ull << lane) - 1)));
        int bs = 0;
        if (lane == leader) bs = atomicAdd(&dcnt[bb], __popcll(m));
        bs = __shfl(bs, leader, 64);
        base = bs + lr;
      }
    }
    brank[n] = base;
    bidx[n] = bb2;
  }
}

// ---- pass 3: tiny — redundant dcnt scan per block + nperm write.
__global__ __launch_bounds__(256) void k_p3(const int* __restrict__ dcnt,
    const int* __restrict__ brank, const int* __restrict__ bidx,
    int* __restrict__ nperm) {
  __shared__ int dsum[16];
  int t = threadIdx.x;
  if (t < 16) {
    int v = dcnt[t];
    int incl = v;
#pragma unroll
    for (int d = 1; d < 16; d <<= 1) {
      int o = __shfl_up(incl, d, 64);
      if (t >= d) incl += o;
    }
    dsum[t] = incl - v;
  }
  __syncthreads();
  int n = blockIdx.x * 256 + t;
  nperm[dsum[bidx[n]] + brank[n]] = n;
}

// ---------------- per-layer message + aggregate + post-matmul ----------------
// Round-0 proven optimum gather loop: 8 nodes/block, quarter-wave per node,
// manual 2-batch statically-indexed pipeline, (128,3) cap, AoS uint4 erec
// records with PLAIN cached loads. ~66us (fast clocks) = compulsory-per-
// XCD gather wall (FETCH ~84MB). LAST fuses relu + @W_out + b_out.
template <int LAST>
__global__ __launch_bounds__(128, 3) void k_msg(const u16* __restrict__ hmain,
    const u16* __restrict__ htail, u16* __restrict__ omain,
    u16* __restrict__ otail,
    const float* __restrict__ w1, const float* __restrict__ w2,
    const float* __restrict__ w3, const float* __restrict__ w4,
    const int* __restrict__ offsets, const int* __restrict__ counts,
    const int* __restrict__ nperm, const uint4* __restrict__ erec,
    const float* __restrict__ Wout, const float* __restrict__ bout,
    float* __restrict__ outp) {
  __shared__ float Rlds[8][4][81];
  int tid = threadIdx.x;
  const int q = tid >> 4;
  const int c = tid & 15;
  const int n = nperm[blockIdx.x * 8 + q];

  float R[4][5];
#pragma unroll
  for (int j = 0; j < 4; j++)
#pragma unroll
    for (int i = 0; i < 5; i++) R[j][i] = 0.f;

  const int start = offsets[n];
  const int degp = (counts[n] + 7) & ~7;
  const int B = degp >> 3;
  const uint2* hrow = (const uint2*)hmain + c;
  const u16* trow = htail + c;

  int i = 0;
  for (; i + 2 <= B; i += 2) {
    const int baseA = start + 8 * i;
    const int baseB = baseA + 8;
    uint4 rA[8], rB[8];
#pragma unroll
    for (int k = 0; k < 8; k++) rA[k] = erec[baseA + k];
#pragma unroll
    for (int k = 0; k < 8; k++) rB[k] = erec[baseB + k];
    uint2 hA[8], hB[8];
    u32 tA[8], tB[8];
#pragma unroll
    for (int k = 0; k < 8; k++) {
      size_t s16 = (size_t)rA[k].x * 16;
      hA[k] = hrow[s16];
      tA[k] = trow[s16];
    }
#pragma unroll
    for (int k = 0; k < 8; k++) {
      size_t s16 = (size_t)rB[k].x * 16;
      hB[k] = hrow[s16];
      tB[k] = trow[s16];
    }
#pragma unroll
    for (int k = 0; k < 8; k++) {
      float A0 = bflo(hA[k].x), A1 = bfhi(hA[k].x);
      float A2 = bflo(hA[k].y), A3 = bfhi(hA[k].y);
      float A4 = bflo(tA[k]);
      float f0 = bflo(rA[k].y), f1 = bfhi(rA[k].y);
      float f2 = bflo(rA[k].z), f3 = bfhi(rA[k].z);
      R[0][0] += f0 * A0; R[0][1] += f0 * A1; R[0][2] += f0 * A2;
      R[0][3] += f0 * A3; R[0][4] += f0 * A4;
      R[1][0] += f1 * A0; R[1][1] += f1 * A1; R[1][2] += f1 * A2;
      R[1][3] += f1 * A3; R[1][4] += f1 * A4;
      R[2][0] += f2 * A0; R[2][1] += f2 * A1; R[2][2] += f2 * A2;
      R[2][3] += f2 * A3; R[2][4] += f2 * A4;
      R[3][0] += f3 * A0; R[3][1] += f3 * A1; R[3][2] += f3 * A2;
      R[3][3] += f3 * A3; R[3][4] += f3 * A4;
    }
#pragma unroll
    for (int k = 0; k < 8; k++) {
      float A0 = bflo(hB[k].x), A1 = bfhi(hB[k].x);
      float A2 = bflo(hB[k].y), A3 = bfhi(hB[k].y);
      float A4 = bflo(tB[k]);
      float f0 = bflo(rB[k].y), f1 = bfhi(rB[k].y);
      float f2 = bflo(rB[k].z), f3 = bfhi(rB[k].z);
      R[0][0] += f0 * A0; R[0][1] += f0 * A1; R[0][2] += f0 * A2;
      R[0][3] += f0 * A3; R[0][4] += f0 * A4;
      R[1][0] += f1 * A0; R[1][1] += f1 * A1; R[1][2] += f1 * A2;
      R[1][3] += f1 * A3; R[1][4] += f1 * A4;
      R[2][0] += f2 * A0; R[2][1] += f2 * A1; R[2][2] += f2 * A2;
      R[2][3] += f2 * A3; R[2][4] += f2 * A4;
      R[3][0] += f3 * A0; R[3][1] += f3 * A1; R[3][2] += f3 * A2;
      R[3][3] += f3 * A3; R[3][4] += f3 * A4;
    }
  }
  if (i < B) {
    const int baseA = start + 8 * i;
    uint4 rA[8];
#pragma unroll
    for (int k = 0; k < 8; k++) rA[k] = erec[baseA + k];
    uint2 hA[8];
    u32 tA[8];
#pragma unroll
    for (int k = 0; k < 8; k++) {
      size_t s16 = (size_t)rA[k].x * 16;
      hA[k] = hrow[s16];
      tA[k] = trow[s16];
    }
#pragma unroll
    for (int k = 0; k < 8; k++) {
      float A0 = bflo(hA[k].x), A1 = bfhi(hA[k].x);
      float A2 = bflo(hA[k].y), A3 = bfhi(hA[k].y);
      float A4 = bflo(tA[k]);
      float f0 = bflo(rA[k].y), f1 = bfhi(rA[k].y);
      float f2 = bflo(rA[k].z), f3 = bfhi(rA[k].z);
      R[0][0] += f0 * A0; R[0][1] += f0 * A1; R[0][2] += f0 * A2;
      R[0][3] += f0 * A3; R[0][4] += f0 * A4;
      R[1][0] += f1 * A0; R[1][1] += f1 * A1; R[1][2] += f1 * A2;
      R[1][3] += f1 * A3; R[1][4] += f1 * A4;
      R[2][0] += f2 * A0; R[2][1] += f2 * A1; R[2][2] += f2 * A2;
      R[2][3] += f2 * A3; R[2][4] += f2 * A4;
      R[3][0] += f3 * A0; R[3][1] += f3 * A1; R[3][2] += f3 * A2;
      R[3][3] += f3 * A3; R[3][4] += f3 * A4;
    }
  }

  // transpose into component-indexed LDS (quarter-private slice, wave-sync)
#pragma unroll
  for (int j = 0; j < 4; j++) {
#pragma unroll
    for (int k = 0; k < 4; k++) Rlds[q][j][4 * c + k] = R[j][k];
    Rlds[q][j][64 + c] = R[j][4];
  }

  // norm constants: 1/sqrt2 * path fan-in norm * 1/sqrt(DEG)
  const float C1 = 0.03125f;      // 1/(sqrt2*sqrt32*4)
  const float C2 = 0.025515518f;  // 1/(sqrt2*sqrt48*4)
  const float C3 = 0.03125f;      // 1/(sqrt2*sqrt32*4)
  const float C4 = 0.044194174f;  // 1/(sqrt2*sqrt16*4)

  u16* opm = omain + (size_t)n * 64;

  // scalar outputs c and c+16, fused over a
  float s0 = 0.f, s1 = 0.f;
#pragma unroll
  for (int a = 0; a < 32; a++) {
    float rs = Rlds[q][0][a];
    s0 += rs * w1[a * 32 + c];
    s1 += rs * w1[a * 32 + c + 16];
  }
  float t0 = 0.f, t1 = 0.f;
#pragma unroll
  for (int a = 0; a < 16; a++) {
    float T = Rlds[q][1][32 + 3 * a] + Rlds[q][2][33 + 3 * a] +
              Rlds[q][3][34 + 3 * a];
    t0 += T * w2[a * 32 + c];
    t1 += T * w2[a * 32 + c + 16];
  }

  float y[8];
  if (LAST) {
#pragma unroll
    for (int j = 0; j < 8; j++) y[j] = 0.f;
    float vs0 = C1 * s0 + C2 * t0;  // comp c
    float vs1 = C1 * s1 + C2 * t1;  // comp c+16
    vs0 = vs0 > 0.f ? vs0 : 0.f;
    vs1 = vs1 > 0.f ? vs1 : 0.f;
#pragma unroll
    for (int j = 0; j < 8; j++)
      y[j] += vs0 * Wout[c * 8 + j] + vs1 * Wout[(c + 16) * 8 + j];
  } else {
    opm[c] = f2bf(C1 * s0 + C2 * t0);
    opm[c + 16] = f2bf(C1 * s1 + C2 * t1);
  }

  // vector outputs: logical comps c2 = 32 + 16*i + c.
#pragma unroll
  for (int v2 = 0; v2 < 3; v2++) {
    int c2 = 32 + 16 * v2 + c;
    int cv = (c2 - 32) / 3, k = (c2 - 32) % 3;
    float a3 = 0.f, a4 = 0.f;
#pragma unroll
    for (int a = 0; a < 32; a++) a3 += Rlds[q][k + 1][a] * w3[a * 16 + cv];
#pragma unroll
    for (int a = 0; a < 16; a++)
      a4 += Rlds[q][0][32 + 3 * a + k] * w4[a * 16 + cv];
    float val = C3 * a3 + C4 * a4;
    if (LAST) {
      val = val > 0.f ? val : 0.f;
#pragma unroll
      for (int j = 0; j < 8; j++) y[j] += val * Wout[c2 * 8 + j];
    } else {
      u16 v = f2bf(val);
      if (v2 < 2) opm[32 + 16 * v2 + c] = v;
      else otail[(size_t)n * 16 + c] = v;
    }
  }

  if (LAST) {
    // quarter-wave (16-lane) reduction; xor masks 1,2,4,8 stay in-quarter
#pragma unroll
    for (int m = 1; m <= 8; m <<= 1) {
#pragma unroll
      for (int j = 0; j < 8; j++) y[j] += __shfl_xor(y[j], m, 64);
    }
    float w = y[0];
#pragma unroll
    for (int j = 1; j < 8; j++)
      if (c == j) w = y[j];
    if (c < 8) outp[(size_t)n * 8 + c] = w + bout[c];
  }
}

extern "C" void kernel_launch(void* const* d_in, const int* in_sizes, int n_in,
                              void* d_out, int out_size, void* d_ws,
                              size_t ws_size, hipStream_t stream) {
  const float* x = (const float*)d_in[0];
  const int* ei = (const int*)d_in[1];
  const float* eattr = (const float*)d_in[2];
  const float* W_in = (const float*)d_in[3];
  const float* b_in = (const float*)d_in[4];
  const float* tp_w1 = (const float*)d_in[5];
  const float* tp_w2 = (const float*)d_in[6];
  const float* tp_w3 = (const float*)d_in[7];
  const float* tp_w4 = (const float*)d_in[8];
  const float* W_out = (const float*)d_in[9];
  const float* b_out = (const float*)d_in[10];
  float* out = (float*)d_out;

  char* ws = (char*)d_ws;
  size_t off = 0;
  auto alloc = [&](size_t bytes) {
    void* p = ws + off;
    off += (bytes + 255) & ~size_t(255);
    return p;
  };
  u16* hm_a = (u16*)alloc((size_t)NN * 64 * 2);
  u16* ht_a = (u16*)alloc((size_t)NN * 16 * 2);
  u16* hm_b = (u16*)alloc((size_t)NN * 64 * 2);
  u16* ht_b = (u16*)alloc((size_t)NN * 16 * 2);
  int* bcnt = (int*)alloc(256 * 4);  // contiguous with dcnt: one memset
  int* dcnt = (int*)alloc(16 * 4);
  int* counts_tot = (int*)alloc((size_t)NN * 4);
  int* offs_fin = (int*)alloc((size_t)NN * 4);
  int* brank = (int*)alloc((size_t)NN * 4);
  int* bidx = (int*)alloc((size_t)NN * 4);
  int* nperm = (int*)alloc((size_t)NN * 4);
  uint4* tmp = (uint4*)alloc((size_t)256 * TCAP * 16);
  uint4* erec = (uint4*)alloc((size_t)256 * ECAP * 16);

  const int* src = ei;
  const int* dst = ei + NE;

  hipMemsetAsync(bcnt, 0, 1024 + 64, stream);  // bcnt[256] + dcnt[16]
  k_p1_in<<<512 + (NN * 10 + 255) / 256, 256, 0, stream>>>(
      dst, src, (const float4*)eattr, bcnt, tmp, x, W_in, b_in, hm_a, ht_a);
  k_p2m<<<256, 512, LCAP * 16, stream>>>(bcnt, tmp, counts_tot, offs_fin,
                                         erec, brank, bidx, dcnt);
  k_p3<<<256, 256, 0, stream>>>(dcnt, brank, bidx, nperm);

  u16* hmi = hm_a;
  u16* hti = ht_a;
  u16* hmo = hm_b;
  u16* hto = ht_b;
  for (int l = 0; l < 2; l++) {
    k_msg<0><<<NN / 8, 128, 0, stream>>>(hmi, hti, hmo, hto, tp_w1 + l * 1024,
                                         tp_w2 + l * 512, tp_w3 + l * 512,
                                         tp_w4 + l * 256, offs_fin, counts_tot,
                                         nperm, erec, W_out, b_out, out);
    u16* t;
    t = hmi; hmi = hmo; hmo = t;
    t = hti; hti = hto; hto = t;
  }
  k_msg<1><<<NN / 8, 128, 0, stream>>>(hmi, hti, hmo, hto, tp_w1 + 2048,
                                       tp_w2 + 1024, tp_w3 + 1024, tp_w4 + 512,
                                       offs_fin, counts_tot, nperm, erec,
                                       W_out, b_out, out);
}

// Round 13
// 336.752 us; speedup vs baseline: 1.0104x; 1.0104x over previous
//
#include <hip/hip_runtime.h>

#define NN 65536
#define NE 1048576
#define HID 80
#define TCAP 8192  // tmp slots per bucket (max raw bucket ~4.4K)
#define ECAP 8192  // erec slots per bucket (max padded bucket ~6.2K)
#define LCAP 4864  // p2m LDS record cache (mean 4096 + 12 sigma)

typedef unsigned int u32;
typedef unsigned short u16;
typedef unsigned long long u64;

typedef float v4f __attribute__((ext_vector_type(4)));

__device__ __forceinline__ u16 f2bf(float f) {
  u32 u = __float_as_uint(f);
  u = (u + 0x7fffu + ((u >> 16) & 1u)) >> 16;  // RNE
  return (u16)u;
}
__device__ __forceinline__ float bfhi(u32 packed) {
  return __uint_as_float(packed & 0xffff0000u);
}
__device__ __forceinline__ float bflo(u32 packed) {
  return __uint_as_float(packed << 16);
}
// nt loads ONLY for true read-once streams (r3/r6: nt on anything L2-reused
// regressed; L2 absorption is the asset on this workload).
__device__ __forceinline__ float4 ntload4f(const float4* p) {
  v4f v = __builtin_nontemporal_load((const v4f*)p);
  return make_float4(v.x, v.y, v.z, v.w);
}
__device__ __forceinline__ int ntloadi(const int* p) {
  return __builtin_nontemporal_load(p);
}

// ---- pass 1: LDS bucket sort (512 blocks, 2048 edges each) ----
// bucket = dst>>8. Per block: LDS hist+scan+scatter, ONE global atomic per
// (block,bucket) run reservation (131K global atomics vs 1M fine-grained),
// contiguous run writes into tmp[bucket]. 2048-edge granularity proven
// (r10: 1024 halved run length to 64B -> partial-line scatter, +13us).
// r13: k_in DELETED — layer 0 gathers x directly (see k_msg<FIRST>).
__global__ __launch_bounds__(256) void k_p1(const int* __restrict__ dst,
    const int* __restrict__ src, const float4* __restrict__ eattr,
    int* __restrict__ bcnt, uint4* __restrict__ tmp) {
  __shared__ int hist[256];
  __shared__ int lofs[257];
  __shared__ int gbase[256];
  __shared__ int sc[256];
  __shared__ uint4 buf[2048];  // 32KB
  __shared__ unsigned char bkid[2048];
  int t = threadIdx.x;
  hist[t] = 0;
  __syncthreads();
  uint4 rec[8];
  int bk[8], lr[8];
  int base = blockIdx.x * 2048 + t;
#pragma unroll
  for (int k = 0; k < 8; k++) {
    int idx = base + k * 256;
    int d = ntloadi(dst + idx);
    float4 ea = ntload4f(eattr + idx);
    int s = ntloadi(src + idx);
    u32 c01 = (u32)f2bf(ea.x) | ((u32)f2bf(ea.y) << 16);
    u32 c23 = (u32)f2bf(ea.z) | ((u32)f2bf(ea.w) << 16);
    rec[k] = make_uint4((u32)s, c01, c23, (u32)d);  // dst in .w
    bk[k] = d >> 8;
    lr[k] = atomicAdd(&hist[bk[k]], 1);  // LDS atomic
  }
  __syncthreads();
  int h = hist[t];
  gbase[t] = atomicAdd(&bcnt[t], h);  // reserve run in bucket t
  sc[t] = h;
  __syncthreads();
  for (int d = 1; d < 256; d <<= 1) {
    int v = (t >= d) ? sc[t - d] : 0;
    __syncthreads();
    sc[t] += v;
    __syncthreads();
  }
  lofs[t] = sc[t] - h;
  if (t == 255) lofs[256] = 2048;
  __syncthreads();
#pragma unroll
  for (int k = 0; k < 8; k++) {
    int slot = lofs[bk[k]] + lr[k];
    buf[slot] = rec[k];
    bkid[slot] = (unsigned char)bk[k];
  }
  __syncthreads();
#pragma unroll
  for (int k = 0; k < 8; k++) {
    int j = t + k * 256;
    int lo = bkid[j];
    tmp[(size_t)lo * TCAP + gbase[lo] + (j - lofs[lo])] = buf[j];
  }
}

// ---- pass 2 (one-pass): one block (512 thr) per bucket, records cached
// in 76KB dynamic LDS during the single tmp sweep. FIXED bucket base
// b*ECAP in erec (holes never read). Then: padded local scan -> counts/
// offs_fin -> place from LDS via cursors -> pad-zero -> classify.
__global__ __launch_bounds__(512) void k_p2m(const int* __restrict__ bcnt,
    const uint4* __restrict__ tmp, int* __restrict__ counts_tot,
    int* __restrict__ offs_fin, uint4* __restrict__ erec,
    int* __restrict__ brank, int* __restrict__ bidx, int* __restrict__ dcnt) {
  extern __shared__ uint4 rbuf[];  // LCAP records, 76KB
  __shared__ int hist[256];
  __shared__ int sc[256];
  __shared__ int noff[256];
  __shared__ int cur[256];
  int t = threadIdx.x;
  if (t < 256) {
    hist[t] = 0;
    cur[t] = 0;
  }
  __syncthreads();
  int b = blockIdx.x;
  int cnt = min(bcnt[b], LCAP);
  const uint4* tb = tmp + (size_t)b * TCAP;
  for (int j = t; j < cnt; j += 512) {
    uint4 r = tb[j];
    rbuf[j] = r;
    atomicAdd(&hist[r.w & 255], 1);  // LDS atomic
  }
  __syncthreads();
  int deg = 0;
  if (t < 256) {
    deg = hist[t];
    sc[t] = (deg + 7) & ~7;
  }
  __syncthreads();
  for (int d = 1; d < 256; d <<= 1) {
    int v = (t < 256 && t >= d) ? sc[t - d] : 0;
    __syncthreads();
    if (t < 256) sc[t] += v;
    __syncthreads();
  }
  if (t < 256) {
    int p = (deg + 7) & ~7;
    int off = b * ECAP + sc[t] - p;
    noff[t] = off;
    offs_fin[b * 256 + t] = off;
    counts_tot[b * 256 + t] = deg;
  }
  __syncthreads();
  for (int j = t; j < cnt; j += 512) {
    uint4 r = rbuf[j];
    int i = r.w & 255;
    int lr = atomicAdd(&cur[i], 1);  // LDS cursor
    erec[(size_t)noff[i] + lr] = make_uint4(r.x, r.y, r.z, 0u);
  }
  __syncthreads();
  if (t < 256) {
    int degp = (deg + 7) & ~7;
    uint4 z = make_uint4(0u, 0u, 0u, 0u);
    for (int e = deg; e < degp; e++) erec[(size_t)noff[t] + e] = z;
    // classify (waves 0..3 fully active -> per-wave ballots complete)
    int n = b * 256 + t;
    int bb2 = 15 - min(degp >> 3, 15);
    int lane = t & 63;
    int base = 0;
#pragma unroll 1
    for (int bb = 0; bb < 16; bb++) {
      u64 m = __ballot(bb2 == bb);
      if (bb2 == bb) {
        int leader = __ffsll((long long)m) - 1;
        int lr = __popcll(m & ((lane == 63) ? ~0ull >> 1 : ((1ull << lane) - 1)));
        int bs = 0;
        if (lane == leader) bs = atomicAdd(&dcnt[bb], __popcll(m));
        bs = __shfl(bs, leader, 64);
        base = bs + lr;
      }
    }
    brank[n] = base;
    bidx[n] = bb2;
  }
}

// ---- pass 3: tiny — redundant dcnt scan per block + nperm write.
__global__ __launch_bounds__(256) void k_p3(const int* __restrict__ dcnt,
    const int* __restrict__ brank, const int* __restrict__ bidx,
    int* __restrict__ nperm) {
  __shared__ int dsum[16];
  int t = threadIdx.x;
  if (t < 16) {
    int v = dcnt[t];
    int incl = v;
#pragma unroll
    for (int d = 1; d < 16; d <<= 1) {
      int o = __shfl_up(incl, d, 64);
      if (t >= d) incl += o;
    }
    dsum[t] = incl - v;
  }
  __syncthreads();
  int n = blockIdx.x * 256 + t;
  nperm[dsum[bidx[n]] + brank[n]] = n;
}

// ---------------- per-layer message + aggregate + post-matmul ----------------
// 8 nodes/block, quarter-wave per node, 2-batch pipeline, (128,3) cap,
// AoS uint4 erec records, PLAIN cached loads.
// FIRST (r13, layer 0): message is bilinear in (h_src, attr) and
// h0 = x@W_in + b_in is LINEAR in x, so aggregation commutes:
//   sum_e B(x_e W + b, a_e) = Bbar(sum_e x_e (x) a_e, sum_e a_e).
// Gather x[src] (64B fp32, one line/edge; 4MB table = per-XCD L2 size)
// instead of h[src] (160B, ~2.6 lines); accumulate M[16][4]+af[4]
// (4 FMA/edge/lane vs 20); apply W_in once per node in the epilogue.
// k_in is deleted; layer-0 numerics IMPROVE (no bf16 rounding of h0).
// LAST (layer 2): fuses relu + @W_out + b_out.
template <int LAST, int FIRST>
__global__ __launch_bounds__(128, 3) void k_msg(const u16* __restrict__ hmain,
    const u16* __restrict__ htail, u16* __restrict__ omain,
    u16* __restrict__ otail,
    const float* __restrict__ w1, const float* __restrict__ w2,
    const float* __restrict__ w3, const float* __restrict__ w4,
    const int* __restrict__ offsets, const int* __restrict__ counts,
    const int* __restrict__ nperm, const uint4* __restrict__ erec,
    const float* __restrict__ Wout, const float* __restrict__ bout,
    float* __restrict__ outp,
    const float* __restrict__ xg, const float* __restrict__ Win,
    const float* __restrict__ bin) {
  __shared__ float Rlds[8][4][81];
  __shared__ float Mlds[8][4][16];  // FIRST only
  int tid = threadIdx.x;
  const int q = tid >> 4;
  const int c = tid & 15;
  const int n = nperm[blockIdx.x * 8 + q];

  const int start = offsets[n];
  const int degp = (counts[n] + 7) & ~7;
  const int B = degp >> 3;

  if (FIRST) {
    // ---- layer-0 gather loop: x[src] + attr outer-product accumulate ----
    float M0 = 0.f, M1 = 0.f, M2 = 0.f, M3 = 0.f;
    float a0 = 0.f, a1 = 0.f, a2 = 0.f, a3 = 0.f;
    const float* xrow = xg + c;
    int i = 0;
    for (; i + 2 <= B; i += 2) {
      const int baseA = start + 8 * i;
      const int baseB = baseA + 8;
      uint4 rA[8], rB[8];
#pragma unroll
      for (int k = 0; k < 8; k++) rA[k] = erec[baseA + k];
#pragma unroll
      for (int k = 0; k < 8; k++) rB[k] = erec[baseB + k];
      float xA[8], xB[8];
#pragma unroll
      for (int k = 0; k < 8; k++) xA[k] = xrow[(size_t)rA[k].x * 16];
#pragma unroll
      for (int k = 0; k < 8; k++) xB[k] = xrow[(size_t)rB[k].x * 16];
#pragma unroll
      for (int k = 0; k < 8; k++) {
        float f0 = bflo(rA[k].y), f1 = bfhi(rA[k].y);
        float f2 = bflo(rA[k].z), f3 = bfhi(rA[k].z);
        M0 += f0 * xA[k]; M1 += f1 * xA[k];
        M2 += f2 * xA[k]; M3 += f3 * xA[k];
        a0 += f0; a1 += f1; a2 += f2; a3 += f3;
      }
#pragma unroll
      for (int k = 0; k < 8; k++) {
        float f0 = bflo(rB[k].y), f1 = bfhi(rB[k].y);
        float f2 = bflo(rB[k].z), f3 = bfhi(rB[k].z);
        M0 += f0 * xB[k]; M1 += f1 * xB[k];
        M2 += f2 * xB[k]; M3 += f3 * xB[k];
        a0 += f0; a1 += f1; a2 += f2; a3 += f3;
      }
    }
    if (i < B) {
      const int baseA = start + 8 * i;
      uint4 rA[8];
#pragma unroll
      for (int k = 0; k < 8; k++) rA[k] = erec[baseA + k];
      float xA[8];
#pragma unroll
      for (int k = 0; k < 8; k++) xA[k] = xrow[(size_t)rA[k].x * 16];
#pragma unroll
      for (int k = 0; k < 8; k++) {
        float f0 = bflo(rA[k].y), f1 = bfhi(rA[k].y);
        float f2 = bflo(rA[k].z), f3 = bfhi(rA[k].z);
        M0 += f0 * xA[k]; M1 += f1 * xA[k];
        M2 += f2 * xA[k]; M3 += f3 * xA[k];
        a0 += f0; a1 += f1; a2 += f2; a3 += f3;
      }
    }
    // expand M -> R via W_in (per-node 16x80 matmul); af carries the bias.
    Mlds[q][0][c] = M0;
    Mlds[q][1][c] = M1;
    Mlds[q][2][c] = M2;
    Mlds[q][3][c] = M3;
    // wave-synchronous within quarter (same assumption as Rlds below)
#pragma unroll
    for (int s2 = 0; s2 < 5; s2++) {
      int a = (s2 < 4) ? (4 * c + s2) : (64 + c);
      float bb = bin[a];
      float r0 = a0 * bb, r1 = a1 * bb, r2 = a2 * bb, r3 = a3 * bb;
#pragma unroll
      for (int cc = 0; cc < 16; cc++) {
        float w = Win[cc * HID + a];
        r0 += Mlds[q][0][cc] * w;
        r1 += Mlds[q][1][cc] * w;
        r2 += Mlds[q][2][cc] * w;
        r3 += Mlds[q][3][cc] * w;
      }
      if (s2 < 4) {
        Rlds[q][0][4 * c + s2] = r0;
        Rlds[q][1][4 * c + s2] = r1;
        Rlds[q][2][4 * c + s2] = r2;
        Rlds[q][3][4 * c + s2] = r3;
      } else {
        Rlds[q][0][64 + c] = r0;
        Rlds[q][1][64 + c] = r1;
        Rlds[q][2][64 + c] = r2;
        Rlds[q][3][64 + c] = r3;
      }
    }
  } else {
    // ---- layers 1/2 gather loop: h[src] (bf16, 160B) ----
    float R[4][5];
#pragma unroll
    for (int j = 0; j < 4; j++)
#pragma unroll
      for (int i2 = 0; i2 < 5; i2++) R[j][i2] = 0.f;
    const uint2* hrow = (const uint2*)hmain + c;
    const u16* trow = htail + c;
    int i = 0;
    for (; i + 2 <= B; i += 2) {
      const int baseA = start + 8 * i;
      const int baseB = baseA + 8;
      uint4 rA[8], rB[8];
#pragma unroll
      for (int k = 0; k < 8; k++) rA[k] = erec[baseA + k];
#pragma unroll
      for (int k = 0; k < 8; k++) rB[k] = erec[baseB + k];
      uint2 hA[8], hB[8];
      u32 tA[8], tB[8];
#pragma unroll
      for (int k = 0; k < 8; k++) {
        size_t s16 = (size_t)rA[k].x * 16;
        hA[k] = hrow[s16];
        tA[k] = trow[s16];
      }
#pragma unroll
      for (int k = 0; k < 8; k++) {
        size_t s16 = (size_t)rB[k].x * 16;
        hB[k] = hrow[s16];
        tB[k] = trow[s16];
      }
#pragma unroll
      for (int k = 0; k < 8; k++) {
        float A0 = bflo(hA[k].x), A1 = bfhi(hA[k].x);
        float A2 = bflo(hA[k].y), A3 = bfhi(hA[k].y);
        float A4 = bflo(tA[k]);
        float f0 = bflo(rA[k].y), f1 = bfhi(rA[k].y);
        float f2 = bflo(rA[k].z), f3 = bfhi(rA[k].z);
        R[0][0] += f0 * A0; R[0][1] += f0 * A1; R[0][2] += f0 * A2;
        R[0][3] += f0 * A3; R[0][4] += f0 * A4;
        R[1][0] += f1 * A0; R[1][1] += f1 * A1; R[1][2] += f1 * A2;
        R[1][3] += f1 * A3; R[1][4] += f1 * A4;
        R[2][0] += f2 * A0; R[2][1] += f2 * A1; R[2][2] += f2 * A2;
        R[2][3] += f2 * A3; R[2][4] += f2 * A4;
        R[3][0] += f3 * A0; R[3][1] += f3 * A1; R[3][2] += f3 * A2;
        R[3][3] += f3 * A3; R[3][4] += f3 * A4;
      }
#pragma unroll
      for (int k = 0; k < 8; k++) {
        float A0 = bflo(hB[k].x), A1 = bfhi(hB[k].x);
        float A2 = bflo(hB[k].y), A3 = bfhi(hB[k].y);
        float A4 = bflo(tB[k]);
        float f0 = bflo(rB[k].y), f1 = bfhi(rB[k].y);
        float f2 = bflo(rB[k].z), f3 = bfhi(rB[k].z);
        R[0][0] += f0 * A0; R[0][1] += f0 * A1; R[0][2] += f0 * A2;
        R[0][3] += f0 * A3; R[0][4] += f0 * A4;
        R[1][0] += f1 * A0; R[1][1] += f1 * A1; R[1][2] += f1 * A2;
        R[1][3] += f1 * A3; R[1][4] += f1 * A4;
        R[2][0] += f2 * A0; R[2][1] += f2 * A1; R[2][2] += f2 * A2;
        R[2][3] += f2 * A3; R[2][4] += f2 * A4;
        R[3][0] += f3 * A0; R[3][1] += f3 * A1; R[3][2] += f3 * A2;
        R[3][3] += f3 * A3; R[3][4] += f3 * A4;
      }
    }
    if (i < B) {
      const int baseA = start + 8 * i;
      uint4 rA[8];
#pragma unroll
      for (int k = 0; k < 8; k++) rA[k] = erec[baseA + k];
      uint2 hA[8];
      u32 tA[8];
#pragma unroll
      for (int k = 0; k < 8; k++) {
        size_t s16 = (size_t)rA[k].x * 16;
        hA[k] = hrow[s16];
        tA[k] = trow[s16];
      }
#pragma unroll
      for (int k = 0; k < 8; k++) {
        float A0 = bflo(hA[k].x), A1 = bfhi(hA[k].x);
        float A2 = bflo(hA[k].y), A3 = bfhi(hA[k].y);
        float A4 = bflo(tA[k]);
        float f0 = bflo(rA[k].y), f1 = bfhi(rA[k].y);
        float f2 = bflo(rA[k].z), f3 = bfhi(rA[k].z);
        R[0][0] += f0 * A0; R[0][1] += f0 * A1; R[0][2] += f0 * A2;
        R[0][3] += f0 * A3; R[0][4] += f0 * A4;
        R[1][0] += f1 * A0; R[1][1] += f1 * A1; R[1][2] += f1 * A2;
        R[1][3] += f1 * A3; R[1][4] += f1 * A4;
        R[2][0] += f2 * A0; R[2][1] += f2 * A1; R[2][2] += f2 * A2;
        R[2][3] += f2 * A3; R[2][4] += f2 * A4;
        R[3][0] += f3 * A0; R[3][1] += f3 * A1; R[3][2] += f3 * A2;
        R[3][3] += f3 * A3; R[3][4] += f3 * A4;
      }
    }
    // transpose into component-indexed LDS (quarter-private, wave-sync)
#pragma unroll
    for (int j = 0; j < 4; j++) {
#pragma unroll
      for (int k = 0; k < 4; k++) Rlds[q][j][4 * c + k] = R[j][k];
      Rlds[q][j][64 + c] = R[j][4];
    }
  }

  // norm constants: 1/sqrt2 * path fan-in norm * 1/sqrt(DEG)
  const float C1 = 0.03125f;      // 1/(sqrt2*sqrt32*4)
  const float C2 = 0.025515518f;  // 1/(sqrt2*sqrt48*4)
  const float C3 = 0.03125f;      // 1/(sqrt2*sqrt32*4)
  const float C4 = 0.044194174f;  // 1/(sqrt2*sqrt16*4)

  u16* opm = omain + (size_t)n * 64;

  // scalar outputs c and c+16, fused over a
  float s0 = 0.f, s1 = 0.f;
#pragma unroll
  for (int a = 0; a < 32; a++) {
    float rs = Rlds[q][0][a];
    s0 += rs * w1[a * 32 + c];
    s1 += rs * w1[a * 32 + c + 16];
  }
  float t0 = 0.f, t1 = 0.f;
#pragma unroll
  for (int a = 0; a < 16; a++) {
    float T = Rlds[q][1][32 + 3 * a] + Rlds[q][2][33 + 3 * a] +
              Rlds[q][3][34 + 3 * a];
    t0 += T * w2[a * 32 + c];
    t1 += T * w2[a * 32 + c + 16];
  }

  float y[8];
  if (LAST) {
#pragma unroll
    for (int j = 0; j < 8; j++) y[j] = 0.f;
    float vs0 = C1 * s0 + C2 * t0;  // comp c
    float vs1 = C1 * s1 + C2 * t1;  // comp c+16
    vs0 = vs0 > 0.f ? vs0 : 0.f;
    vs1 = vs1 > 0.f ? vs1 : 0.f;
#pragma unroll
    for (int j = 0; j < 8; j++)
      y[j] += vs0 * Wout[c * 8 + j] + vs1 * Wout[(c + 16) * 8 + j];
  } else {
    opm[c] = f2bf(C1 * s0 + C2 * t0);
    opm[c + 16] = f2bf(C1 * s1 + C2 * t1);
  }

  // vector outputs: logical comps c2 = 32 + 16*i + c.
#pragma unroll
  for (int v2 = 0; v2 < 3; v2++) {
    int c2 = 32 + 16 * v2 + c;
    int cv = (c2 - 32) / 3, k = (c2 - 32) % 3;
    float a3 = 0.f, a4 = 0.f;
#pragma unroll
    for (int a = 0; a < 32; a++) a3 += Rlds[q][k + 1][a] * w3[a * 16 + cv];
#pragma unroll
    for (int a = 0; a < 16; a++)
      a4 += Rlds[q][0][32 + 3 * a + k] * w4[a * 16 + cv];
    float val = C3 * a3 + C4 * a4;
    if (LAST) {
      val = val > 0.f ? val : 0.f;
#pragma unroll
      for (int j = 0; j < 8; j++) y[j] += val * Wout[c2 * 8 + j];
    } else {
      u16 v = f2bf(val);
      if (v2 < 2) opm[32 + 16 * v2 + c] = v;
      else otail[(size_t)n * 16 + c] = v;
    }
  }

  if (LAST) {
    // quarter-wave (16-lane) reduction; xor masks 1,2,4,8 stay in-quarter
#pragma unroll
    for (int m = 1; m <= 8; m <<= 1) {
#pragma unroll
      for (int j = 0; j < 8; j++) y[j] += __shfl_xor(y[j], m, 64);
    }
    float w = y[0];
#pragma unroll
    for (int j = 1; j < 8; j++)
      if (c == j) w = y[j];
    if (c < 8) outp[(size_t)n * 8 + c] = w + bout[c];
  }
}

extern "C" void kernel_launch(void* const* d_in, const int* in_sizes, int n_in,
                              void* d_out, int out_size, void* d_ws,
                              size_t ws_size, hipStream_t stream) {
  const float* x = (const float*)d_in[0];
  const int* ei = (const int*)d_in[1];
  const float* eattr = (const float*)d_in[2];
  const float* W_in = (const float*)d_in[3];
  const float* b_in = (const float*)d_in[4];
  const float* tp_w1 = (const float*)d_in[5];
  const float* tp_w2 = (const float*)d_in[6];
  const float* tp_w3 = (const float*)d_in[7];
  const float* tp_w4 = (const float*)d_in[8];
  const float* W_out = (const float*)d_in[9];
  const float* b_out = (const float*)d_in[10];
  float* out = (float*)d_out;

  char* ws = (char*)d_ws;
  size_t off = 0;
  auto alloc = [&](size_t bytes) {
    void* p = ws + off;
    off += (bytes + 255) & ~size_t(255);
    return p;
  };
  u16* hm_a = (u16*)alloc((size_t)NN * 64 * 2);
  u16* ht_a = (u16*)alloc((size_t)NN * 16 * 2);
  u16* hm_b = (u16*)alloc((size_t)NN * 64 * 2);
  u16* ht_b = (u16*)alloc((size_t)NN * 16 * 2);
  int* bcnt = (int*)alloc(256 * 4);  // contiguous with dcnt: one memset
  int* dcnt = (int*)alloc(16 * 4);
  int* counts_tot = (int*)alloc((size_t)NN * 4);
  int* offs_fin = (int*)alloc((size_t)NN * 4);
  int* brank = (int*)alloc((size_t)NN * 4);
  int* bidx = (int*)alloc((size_t)NN * 4);
  int* nperm = (int*)alloc((size_t)NN * 4);
  uint4* tmp = (uint4*)alloc((size_t)256 * TCAP * 16);
  uint4* erec = (uint4*)alloc((size_t)256 * ECAP * 16);

  const int* src = ei;
  const int* dst = ei + NE;

  hipMemsetAsync(bcnt, 0, 1024 + 64, stream);  // bcnt[256] + dcnt[16]
  k_p1<<<512, 256, 0, stream>>>(dst, src, (const float4*)eattr, bcnt, tmp);
  k_p2m<<<256, 512, LCAP * 16, stream>>>(bcnt, tmp, counts_tot, offs_fin,
                                         erec, brank, bidx, dcnt);
  k_p3<<<256, 256, 0, stream>>>(dcnt, brank, bidx, nperm);

  // layer 0: FIRST=1, gathers x directly (h0 never materialized)
  k_msg<0, 1><<<NN / 8, 128, 0, stream>>>(
      nullptr, nullptr, hm_b, ht_b, tp_w1, tp_w2, tp_w3, tp_w4, offs_fin,
      counts_tot, nperm, erec, W_out, b_out, out, x, W_in, b_in);
  // layer 1
  k_msg<0, 0><<<NN / 8, 128, 0, stream>>>(
      hm_b, ht_b, hm_a, ht_a, tp_w1 + 1024, tp_w2 + 512, tp_w3 + 512,
      tp_w4 + 256, offs_fin, counts_tot, nperm, erec, W_out, b_out, out, x,
      W_in, b_in);
  // layer 2: LAST=1, fused relu + W_out
  k_msg<1, 0><<<NN / 8, 128, 0, stream>>>(
      hm_a, ht_a, hm_b, ht_b, tp_w1 + 2048, tp_w2 + 1024, tp_w3 + 1024,
      tp_w4 + 512, offs_fin, counts_tot, nperm, erec, W_out, b_out, out, x,
      W_in, b_in);
}

// Round 14
// 332.781 us; speedup vs baseline: 1.0224x; 1.0119x over previous
//
#include <hip/hip_runtime.h>

#define NN 65536
#define NE 1048576
#define HID 80
#define TCAP 8192  // tmp slots per bucket (max raw bucket ~4.4K)
#define ECAP 8192  // erec slots per bucket (max padded bucket ~6.2K)
#define LCAP 4608  // p2m LDS cache: mean 4096 + 8 sigma; 72KB -> 2 blocks/CU

typedef unsigned int u32;
typedef unsigned short u16;
typedef unsigned long long u64;

typedef float v4f __attribute__((ext_vector_type(4)));

__device__ __forceinline__ u16 f2bf(float f) {
  u32 u = __float_as_uint(f);
  u = (u + 0x7fffu + ((u >> 16) & 1u)) >> 16;  // RNE
  return (u16)u;
}
__device__ __forceinline__ float bfhi(u32 packed) {
  return __uint_as_float(packed & 0xffff0000u);
}
__device__ __forceinline__ float bflo(u32 packed) {
  return __uint_as_float(packed << 16);
}
// nt loads ONLY for true read-once streams (r3/r6: nt on anything L2-reused
// regressed; L2 absorption is the asset on this workload).
__device__ __forceinline__ float4 ntload4f(const float4* p) {
  v4f v = __builtin_nontemporal_load((const v4f*)p);
  return make_float4(v.x, v.y, v.z, v.w);
}
__device__ __forceinline__ int ntloadi(const int* p) {
  return __builtin_nontemporal_load(p);
}

// ---- pass 1: LDS bucket sort (512 blocks, 2048 edges each) ----
// bucket = dst>>8. Per block: LDS hist+scan+scatter, ONE global atomic per
// (block,bucket) run reservation (131K global atomics vs 1M fine-grained),
// contiguous run writes into tmp[bucket]. 2048-edge granularity proven
// (r10: 1024 halved run length to 64B -> partial-line scatter, +13us).
__global__ __launch_bounds__(256) void k_p1(const int* __restrict__ dst,
    const int* __restrict__ src, const float4* __restrict__ eattr,
    int* __restrict__ bcnt, uint4* __restrict__ tmp) {
  __shared__ int hist[256];
  __shared__ int lofs[257];
  __shared__ int gbase[256];
  __shared__ int sc[256];
  __shared__ uint4 buf[2048];  // 32KB
  __shared__ unsigned char bkid[2048];
  int t = threadIdx.x;
  hist[t] = 0;
  __syncthreads();
  uint4 rec[8];
  int bk[8], lr[8];
  int base = blockIdx.x * 2048 + t;
#pragma unroll
  for (int k = 0; k < 8; k++) {
    int idx = base + k * 256;
    int d = ntloadi(dst + idx);
    float4 ea = ntload4f(eattr + idx);
    int s = ntloadi(src + idx);
    u32 c01 = (u32)f2bf(ea.x) | ((u32)f2bf(ea.y) << 16);
    u32 c23 = (u32)f2bf(ea.z) | ((u32)f2bf(ea.w) << 16);
    rec[k] = make_uint4((u32)s, c01, c23, (u32)d);  // dst in .w
    bk[k] = d >> 8;
    lr[k] = atomicAdd(&hist[bk[k]], 1);  // LDS atomic
  }
  __syncthreads();
  int h = hist[t];
  gbase[t] = atomicAdd(&bcnt[t], h);  // reserve run in bucket t
  sc[t] = h;
  __syncthreads();
  for (int d = 1; d < 256; d <<= 1) {
    int v = (t >= d) ? sc[t - d] : 0;
    __syncthreads();
    sc[t] += v;
    __syncthreads();
  }
  lofs[t] = sc[t] - h;
  if (t == 255) lofs[256] = 2048;
  __syncthreads();
#pragma unroll
  for (int k = 0; k < 8; k++) {
    int slot = lofs[bk[k]] + lr[k];
    buf[slot] = rec[k];
    bkid[slot] = (unsigned char)bk[k];
  }
  __syncthreads();
#pragma unroll
  for (int k = 0; k < 8; k++) {
    int j = t + k * 256;
    int lo = bkid[j];
    tmp[(size_t)lo * TCAP + gbase[lo] + (j - lofs[lo])] = buf[j];
  }
}

// ---- pass 2 (one-pass): one block (512 thr) per bucket, records cached
// in 72KB dynamic LDS during the single tmp sweep (r14: LCAP 4864->4608
// so dynamic+static = 76KB < 80KB -> CERTAIN 2 blocks/CU; at 4864 it sat
// exactly at the 80KB boundary). FIXED bucket base b*ECAP in erec.
// Then: padded local scan -> counts/offs_fin -> place from LDS via
// cursors -> pad-zero -> classify (reversed: heaviest first).
__global__ __launch_bounds__(512, 4) void k_p2m(const int* __restrict__ bcnt,
    const uint4* __restrict__ tmp, int* __restrict__ counts_tot,
    int* __restrict__ offs_fin, uint4* __restrict__ erec,
    int* __restrict__ brank, int* __restrict__ bidx, int* __restrict__ dcnt) {
  extern __shared__ uint4 rbuf[];  // LCAP records, 72KB
  __shared__ int hist[256];
  __shared__ int sc[256];
  __shared__ int noff[256];
  __shared__ int cur[256];
  int t = threadIdx.x;
  if (t < 256) {
    hist[t] = 0;
    cur[t] = 0;
  }
  __syncthreads();
  int b = blockIdx.x;
  int cnt = min(bcnt[b], LCAP);
  const uint4* tb = tmp + (size_t)b * TCAP;
  for (int j = t; j < cnt; j += 512) {
    uint4 r = tb[j];
    rbuf[j] = r;
    atomicAdd(&hist[r.w & 255], 1);  // LDS atomic
  }
  __syncthreads();
  int deg = 0;
  if (t < 256) {
    deg = hist[t];
    sc[t] = (deg + 7) & ~7;
  }
  __syncthreads();
  for (int d = 1; d < 256; d <<= 1) {
    int v = (t < 256 && t >= d) ? sc[t - d] : 0;
    __syncthreads();
    if (t < 256) sc[t] += v;
    __syncthreads();
  }
  if (t < 256) {
    int p = (deg + 7) & ~7;
    int off = b * ECAP + sc[t] - p;
    noff[t] = off;
    offs_fin[b * 256 + t] = off;
    counts_tot[b * 256 + t] = deg;
  }
  __syncthreads();
  for (int j = t; j < cnt; j += 512) {
    uint4 r = rbuf[j];
    int i = r.w & 255;
    int lr = atomicAdd(&cur[i], 1);  // LDS cursor
    erec[(size_t)noff[i] + lr] = make_uint4(r.x, r.y, r.z, 0u);
  }
  __syncthreads();
  if (t < 256) {
    int degp = (deg + 7) & ~7;
    uint4 z = make_uint4(0u, 0u, 0u, 0u);
    for (int e = deg; e < degp; e++) erec[(size_t)noff[t] + e] = z;
    // classify (waves 0..3 fully active -> per-wave ballots complete)
    int n = b * 256 + t;
    int bb2 = 15 - min(degp >> 3, 15);
    int lane = t & 63;
    int base = 0;
#pragma unroll 1
    for (int bb = 0; bb < 16; bb++) {
      u64 m = __ballot(bb2 == bb);
      if (bb2 == bb) {
        int leader = __ffsll((long long)m) - 1;
        int lr = __popcll(m & ((lane == 63) ? ~0ull >> 1 : ((1ull << lane) - 1)));
        int bs = 0;
        if (lane == leader) bs = atomicAdd(&dcnt[bb], __popcll(m));
        bs = __shfl(bs, leader, 64);
        base = bs + lr;
      }
    }
    brank[n] = base;
    bidx[n] = bb2;
  }
}

// ---- pass 3: tiny — redundant dcnt scan per block + nperm write.
__global__ __launch_bounds__(256) void k_p3(const int* __restrict__ dcnt,
    const int* __restrict__ brank, const int* __restrict__ bidx,
    int* __restrict__ nperm) {
  __shared__ int dsum[16];
  int t = threadIdx.x;
  if (t < 16) {
    int v = dcnt[t];
    int incl = v;
#pragma unroll
    for (int d = 1; d < 16; d <<= 1) {
      int o = __shfl_up(incl, d, 64);
      if (t >= d) incl += o;
    }
    dsum[t] = incl - v;
  }
  __syncthreads();
  int n = blockIdx.x * 256 + t;
  nperm[dsum[bidx[n]] + brank[n]] = n;
}

// ---------------- per-layer message + aggregate + post-matmul ----------------
// 8 nodes/block, quarter-wave per node, 2-batch pipeline, (128,3) cap,
// AoS uint4 erec records, PLAIN cached loads.
// FIRST (layer 0): message is bilinear in (h_src, attr), h0 = x@W_in + b
// is LINEAR in x -> aggregation commutes. Gather x[src] (64B fp32, 1
// line/edge) instead of h (160B, ~2.5 lines); accumulate M[16][4]+af[4];
// apply W_in per node in the epilogue. k_in deleted; layer-0 fp32 (absmax
// improved 0.0234->0.0171). r14: Mlds padded to [17] — at [16] the
// q-stride (64 floats = 0 mod 32 banks) made all 4 quarters of a wave hit
// the same bank on every broadcast read: 6.65M bank conflicts, ~+4us.
// LAST (layer 2): fuses relu + @W_out + b_out.
template <int LAST, int FIRST>
__global__ __launch_bounds__(128, 3) void k_msg(const u16* __restrict__ hmain,
    const u16* __restrict__ htail, u16* __restrict__ omain,
    u16* __restrict__ otail,
    const float* __restrict__ w1, const float* __restrict__ w2,
    const float* __restrict__ w3, const float* __restrict__ w4,
    const int* __restrict__ offsets, const int* __restrict__ counts,
    const int* __restrict__ nperm, const uint4* __restrict__ erec,
    const float* __restrict__ Wout, const float* __restrict__ bout,
    float* __restrict__ outp,
    const float* __restrict__ xg, const float* __restrict__ Win,
    const float* __restrict__ bin) {
  __shared__ float Rlds[8][4][81];
  __shared__ float Mlds[8][4][17];  // FIRST only; padded (bank-conflict fix)
  int tid = threadIdx.x;
  const int q = tid >> 4;
  const int c = tid & 15;
  const int n = nperm[blockIdx.x * 8 + q];

  const int start = offsets[n];
  const int degp = (counts[n] + 7) & ~7;
  const int B = degp >> 3;

  if (FIRST) {
    // ---- layer-0 gather loop: x[src] + attr outer-product accumulate ----
    float M0 = 0.f, M1 = 0.f, M2 = 0.f, M3 = 0.f;
    float a0 = 0.f, a1 = 0.f, a2 = 0.f, a3 = 0.f;
    const float* xrow = xg + c;
    int i = 0;
    for (; i + 2 <= B; i += 2) {
      const int baseA = start + 8 * i;
      const int baseB = baseA + 8;
      uint4 rA[8], rB[8];
#pragma unroll
      for (int k = 0; k < 8; k++) rA[k] = erec[baseA + k];
#pragma unroll
      for (int k = 0; k < 8; k++) rB[k] = erec[baseB + k];
      float xA[8], xB[8];
#pragma unroll
      for (int k = 0; k < 8; k++) xA[k] = xrow[(size_t)rA[k].x * 16];
#pragma unroll
      for (int k = 0; k < 8; k++) xB[k] = xrow[(size_t)rB[k].x * 16];
#pragma unroll
      for (int k = 0; k < 8; k++) {
        float f0 = bflo(rA[k].y), f1 = bfhi(rA[k].y);
        float f2 = bflo(rA[k].z), f3 = bfhi(rA[k].z);
        M0 += f0 * xA[k]; M1 += f1 * xA[k];
        M2 += f2 * xA[k]; M3 += f3 * xA[k];
        a0 += f0; a1 += f1; a2 += f2; a3 += f3;
      }
#pragma unroll
      for (int k = 0; k < 8; k++) {
        float f0 = bflo(rB[k].y), f1 = bfhi(rB[k].y);
        float f2 = bflo(rB[k].z), f3 = bfhi(rB[k].z);
        M0 += f0 * xB[k]; M1 += f1 * xB[k];
        M2 += f2 * xB[k]; M3 += f3 * xB[k];
        a0 += f0; a1 += f1; a2 += f2; a3 += f3;
      }
    }
    if (i < B) {
      const int baseA = start + 8 * i;
      uint4 rA[8];
#pragma unroll
      for (int k = 0; k < 8; k++) rA[k] = erec[baseA + k];
      float xA[8];
#pragma unroll
      for (int k = 0; k < 8; k++) xA[k] = xrow[(size_t)rA[k].x * 16];
#pragma unroll
      for (int k = 0; k < 8; k++) {
        float f0 = bflo(rA[k].y), f1 = bfhi(rA[k].y);
        float f2 = bflo(rA[k].z), f3 = bfhi(rA[k].z);
        M0 += f0 * xA[k]; M1 += f1 * xA[k];
        M2 += f2 * xA[k]; M3 += f3 * xA[k];
        a0 += f0; a1 += f1; a2 += f2; a3 += f3;
      }
    }
    // expand M -> R via W_in (per-node 16x80 matmul); af carries the bias.
    Mlds[q][0][c] = M0;
    Mlds[q][1][c] = M1;
    Mlds[q][2][c] = M2;
    Mlds[q][3][c] = M3;
    // wave-synchronous within quarter (same assumption as Rlds below)
#pragma unroll
    for (int s2 = 0; s2 < 5; s2++) {
      int a = (s2 < 4) ? (4 * c + s2) : (64 + c);
      float bb = bin[a];
      float r0 = a0 * bb, r1 = a1 * bb, r2 = a2 * bb, r3 = a3 * bb;
#pragma unroll
      for (int cc = 0; cc < 16; cc++) {
        float w = Win[cc * HID + a];
        r0 += Mlds[q][0][cc] * w;
        r1 += Mlds[q][1][cc] * w;
        r2 += Mlds[q][2][cc] * w;
        r3 += Mlds[q][3][cc] * w;
      }
      if (s2 < 4) {
        Rlds[q][0][4 * c + s2] = r0;
        Rlds[q][1][4 * c + s2] = r1;
        Rlds[q][2][4 * c + s2] = r2;
        Rlds[q][3][4 * c + s2] = r3;
      } else {
        Rlds[q][0][64 + c] = r0;
        Rlds[q][1][64 + c] = r1;
        Rlds[q][2][64 + c] = r2;
        Rlds[q][3][64 + c] = r3;
      }
    }
  } else {
    // ---- layers 1/2 gather loop: h[src] (bf16, 160B) ----
    float R[4][5];
#pragma unroll
    for (int j = 0; j < 4; j++)
#pragma unroll
      for (int i2 = 0; i2 < 5; i2++) R[j][i2] = 0.f;
    const uint2* hrow = (const uint2*)hmain + c;
    const u16* trow = htail + c;
    int i = 0;
    for (; i + 2 <= B; i += 2) {
      const int baseA = start + 8 * i;
      const int baseB = baseA + 8;
      uint4 rA[8], rB[8];
#pragma unroll
      for (int k = 0; k < 8; k++) rA[k] = erec[baseA + k];
#pragma unroll
      for (int k = 0; k < 8; k++) rB[k] = erec[baseB + k];
      uint2 hA[8], hB[8];
      u32 tA[8], tB[8];
#pragma unroll
      for (int k = 0; k < 8; k++) {
        size_t s16 = (size_t)rA[k].x * 16;
        hA[k] = hrow[s16];
        tA[k] = trow[s16];
      }
#pragma unroll
      for (int k = 0; k < 8; k++) {
        size_t s16 = (size_t)rB[k].x * 16;
        hB[k] = hrow[s16];
        tB[k] = trow[s16];
      }
#pragma unroll
      for (int k = 0; k < 8; k++) {
        float A0 = bflo(hA[k].x), A1 = bfhi(hA[k].x);
        float A2 = bflo(hA[k].y), A3 = bfhi(hA[k].y);
        float A4 = bflo(tA[k]);
        float f0 = bflo(rA[k].y), f1 = bfhi(rA[k].y);
        float f2 = bflo(rA[k].z), f3 = bfhi(rA[k].z);
        R[0][0] += f0 * A0; R[0][1] += f0 * A1; R[0][2] += f0 * A2;
        R[0][3] += f0 * A3; R[0][4] += f0 * A4;
        R[1][0] += f1 * A0; R[1][1] += f1 * A1; R[1][2] += f1 * A2;
        R[1][3] += f1 * A3; R[1][4] += f1 * A4;
        R[2][0] += f2 * A0; R[2][1] += f2 * A1; R[2][2] += f2 * A2;
        R[2][3] += f2 * A3; R[2][4] += f2 * A4;
        R[3][0] += f3 * A0; R[3][1] += f3 * A1; R[3][2] += f3 * A2;
        R[3][3] += f3 * A3; R[3][4] += f3 * A4;
      }
#pragma unroll
      for (int k = 0; k < 8; k++) {
        float A0 = bflo(hB[k].x), A1 = bfhi(hB[k].x);
        float A2 = bflo(hB[k].y), A3 = bfhi(hB[k].y);
        float A4 = bflo(tB[k]);
        float f0 = bflo(rB[k].y), f1 = bfhi(rB[k].y);
        float f2 = bflo(rB[k].z), f3 = bfhi(rB[k].z);
        R[0][0] += f0 * A0; R[0][1] += f0 * A1; R[0][2] += f0 * A2;
        R[0][3] += f0 * A3; R[0][4] += f0 * A4;
        R[1][0] += f1 * A0; R[1][1] += f1 * A1; R[1][2] += f1 * A2;
        R[1][3] += f1 * A3; R[1][4] += f1 * A4;
        R[2][0] += f2 * A0; R[2][1] += f2 * A1; R[2][2] += f2 * A2;
        R[2][3] += f2 * A3; R[2][4] += f2 * A4;
        R[3][0] += f3 * A0; R[3][1] += f3 * A1; R[3][2] += f3 * A2;
        R[3][3] += f3 * A3; R[3][4] += f3 * A4;
      }
    }
    if (i < B) {
      const int baseA = start + 8 * i;
      uint4 rA[8];
#pragma unroll
      for (int k = 0; k < 8; k++) rA[k] = erec[baseA + k];
      uint2 hA[8];
      u32 tA[8];
#pragma unroll
      for (int k = 0; k < 8; k++) {
        size_t s16 = (size_t)rA[k].x * 16;
        hA[k] = hrow[s16];
        tA[k] = trow[s16];
      }
#pragma unroll
      for (int k = 0; k < 8; k++) {
        float A0 = bflo(hA[k].x), A1 = bfhi(hA[k].x);
        float A2 = bflo(hA[k].y), A3 = bfhi(hA[k].y);
        float A4 = bflo(tA[k]);
        float f0 = bflo(rA[k].y), f1 = bfhi(rA[k].y);
        float f2 = bflo(rA[k].z), f3 = bfhi(rA[k].z);
        R[0][0] += f0 * A0; R[0][1] += f0 * A1; R[0][2] += f0 * A2;
        R[0][3] += f0 * A3; R[0][4] += f0 * A4;
        R[1][0] += f1 * A0; R[1][1] += f1 * A1; R[1][2] += f1 * A2;
        R[1][3] += f1 * A3; R[1][4] += f1 * A4;
        R[2][0] += f2 * A0; R[2][1] += f2 * A1; R[2][2] += f2 * A2;
        R[2][3] += f2 * A3; R[2][4] += f2 * A4;
        R[3][0] += f3 * A0; R[3][1] += f3 * A1; R[3][2] += f3 * A2;
        R[3][3] += f3 * A3; R[3][4] += f3 * A4;
      }
    }
    // transpose into component-indexed LDS (quarter-private, wave-sync)
#pragma unroll
    for (int j = 0; j < 4; j++) {
#pragma unroll
      for (int k = 0; k < 4; k++) Rlds[q][j][4 * c + k] = R[j][k];
      Rlds[q][j][64 + c] = R[j][4];
    }
  }

  // norm constants: 1/sqrt2 * path fan-in norm * 1/sqrt(DEG)
  const float C1 = 0.03125f;      // 1/(sqrt2*sqrt32*4)
  const float C2 = 0.025515518f;  // 1/(sqrt2*sqrt48*4)
  const float C3 = 0.03125f;      // 1/(sqrt2*sqrt32*4)
  const float C4 = 0.044194174f;  // 1/(sqrt2*sqrt16*4)

  u16* opm = omain + (size_t)n * 64;

  // scalar outputs c and c+16, fused over a
  float s0 = 0.f, s1 = 0.f;
#pragma unroll
  for (int a = 0; a < 32; a++) {
    float rs = Rlds[q][0][a];
    s0 += rs * w1[a * 32 + c];
    s1 += rs * w1[a * 32 + c + 16];
  }
  float t0 = 0.f, t1 = 0.f;
#pragma unroll
  for (int a = 0; a < 16; a++) {
    float T = Rlds[q][1][32 + 3 * a] + Rlds[q][2][33 + 3 * a] +
              Rlds[q][3][34 + 3 * a];
    t0 += T * w2[a * 32 + c];
    t1 += T * w2[a * 32 + c + 16];
  }

  float y[8];
  if (LAST) {
#pragma unroll
    for (int j = 0; j < 8; j++) y[j] = 0.f;
    float vs0 = C1 * s0 + C2 * t0;  // comp c
    float vs1 = C1 * s1 + C2 * t1;  // comp c+16
    vs0 = vs0 > 0.f ? vs0 : 0.f;
    vs1 = vs1 > 0.f ? vs1 : 0.f;
#pragma unroll
    for (int j = 0; j < 8; j++)
      y[j] += vs0 * Wout[c * 8 + j] + vs1 * Wout[(c + 16) * 8 + j];
  } else {
    opm[c] = f2bf(C1 * s0 + C2 * t0);
    opm[c + 16] = f2bf(C1 * s1 + C2 * t1);
  }

  // vector outputs: logical comps c2 = 32 + 16*i + c.
#pragma unroll
  for (int v2 = 0; v2 < 3; v2++) {
    int c2 = 32 + 16 * v2 + c;
    int cv = (c2 - 32) / 3, k = (c2 - 32) % 3;
    float a3 = 0.f, a4 = 0.f;
#pragma unroll
    for (int a = 0; a < 32; a++) a3 += Rlds[q][k + 1][a] * w3[a * 16 + cv];
#pragma unroll
    for (int a = 0; a < 16; a++)
      a4 += Rlds[q][0][32 + 3 * a + k] * w4[a * 16 + cv];
    float val = C3 * a3 + C4 * a4;
    if (LAST) {
      val = val > 0.f ? val : 0.f;
#pragma unroll
      for (int j = 0; j < 8; j++) y[j] += val * Wout[c2 * 8 + j];
    } else {
      u16 v = f2bf(val);
      if (v2 < 2) opm[32 + 16 * v2 + c] = v;
      else otail[(size_t)n * 16 + c] = v;
    }
  }

  if (LAST) {
    // quarter-wave (16-lane) reduction; xor masks 1,2,4,8 stay in-quarter
#pragma unroll
    for (int m = 1; m <= 8; m <<= 1) {
#pragma unroll
      for (int j = 0; j < 8; j++) y[j] += __shfl_xor(y[j], m, 64);
    }
    float w = y[0];
#pragma unroll
    for (int j = 1; j < 8; j++)
      if (c == j) w = y[j];
    if (c < 8) outp[(size_t)n * 8 + c] = w + bout[c];
  }
}

extern "C" void kernel_launch(void* const* d_in, const int* in_sizes, int n_in,
                              void* d_out, int out_size, void* d_ws,
                              size_t ws_size, hipStream_t stream) {
  const float* x = (const float*)d_in[0];
  const int* ei = (const int*)d_in[1];
  const float* eattr = (const float*)d_in[2];
  const float* W_in = (const float*)d_in[3];
  const float* b_in = (const float*)d_in[4];
  const float* tp_w1 = (const float*)d_in[5];
  const float* tp_w2 = (const float*)d_in[6];
  const float* tp_w3 = (const float*)d_in[7];
  const float* tp_w4 = (const float*)d_in[8];
  const float* W_out = (const float*)d_in[9];
  const float* b_out = (const float*)d_in[10];
  float* out = (float*)d_out;

  char* ws = (char*)d_ws;
  size_t off = 0;
  auto alloc = [&](size_t bytes) {
    void* p = ws + off;
    off += (bytes + 255) & ~size_t(255);
    return p;
  };
  u16* hm_a = (u16*)alloc((size_t)NN * 64 * 2);
  u16* ht_a = (u16*)alloc((size_t)NN * 16 * 2);
  u16* hm_b = (u16*)alloc((size_t)NN * 64 * 2);
  u16* ht_b = (u16*)alloc((size_t)NN * 16 * 2);
  int* bcnt = (int*)alloc(256 * 4);  // contiguous with dcnt: one memset
  int* dcnt = (int*)alloc(16 * 4);
  int* counts_tot = (int*)alloc((size_t)NN * 4);
  int* offs_fin = (int*)alloc((size_t)NN * 4);
  int* brank = (int*)alloc((size_t)NN * 4);
  int* bidx = (int*)alloc((size_t)NN * 4);
  int* nperm = (int*)alloc((size_t)NN * 4);
  uint4* tmp = (uint4*)alloc((size_t)256 * TCAP * 16);
  uint4* erec = (uint4*)alloc((size_t)256 * ECAP * 16);

  const int* src = ei;
  const int* dst = ei + NE;

  hipMemsetAsync(bcnt, 0, 1024 + 64, stream);  // bcnt[256] + dcnt[16]
  k_p1<<<512, 256, 0, stream>>>(dst, src, (const float4*)eattr, bcnt, tmp);
  k_p2m<<<256, 512, LCAP * 16, stream>>>(bcnt, tmp, counts_tot, offs_fin,
                                         erec, brank, bidx, dcnt);
  k_p3<<<256, 256, 0, stream>>>(dcnt, brank, bidx, nperm);

  // layer 0: FIRST=1, gathers x directly (h0 never materialized)
  k_msg<0, 1><<<NN / 8, 128, 0, stream>>>(
      nullptr, nullptr, hm_b, ht_b, tp_w1, tp_w2, tp_w3, tp_w4, offs_fin,
      counts_tot, nperm, erec, W_out, b_out, out, x, W_in, b_in);
  // layer 1
  k_msg<0, 0><<<NN / 8, 128, 0, stream>>>(
      hm_b, ht_b, hm_a, ht_a, tp_w1 + 1024, tp_w2 + 512, tp_w3 + 512,
      tp_w4 + 256, offs_fin, counts_tot, nperm, erec, W_out, b_out, out, x,
      W_in, b_in);
  // layer 2: LAST=1, fused relu + W_out
  k_msg<1, 0><<<NN / 8, 128, 0, stream>>>(
      hm_a, ht_a, hm_b, ht_b, tp_w1 + 2048, tp_w2 + 1024, tp_w3 + 1024,
      tp_w4 + 512, offs_fin, counts_tot, nperm, erec, W_out, b_out, out, x,
      W_in, b_in);
}